// Round 1
// baseline (2337.511 us; speedup 1.0000x reference)
//
#include <hip/hip_runtime.h>

typedef __bf16 bf16;
typedef __bf16 bf16x8 __attribute__((ext_vector_type(8)));
typedef __bf16 bf16x4 __attribute__((ext_vector_type(4)));
typedef float f32x4 __attribute__((ext_vector_type(4)));

// direct global->LDS DMA, 16B per lane (dest must be linear: uniform base + lane*16)
#define GLOAD16(gptr, lptr)                                        \
  __builtin_amdgcn_global_load_lds(                                \
      (const __attribute__((address_space(1))) void*)(gptr),       \
      (__attribute__((address_space(3))) void*)(lptr), 16, 0, 0)

// ---------------- embedding: x = tok_emb[idx] + pos_emb ----------------
__global__ __launch_bounds__(256) void embed_kernel(
    const int* __restrict__ idx, const float* __restrict__ tok,
    const float* __restrict__ pos, float* __restrict__ x) {
  int row = blockIdx.x;           // b*1024 + t
  int t = row & 1023;
  int token = idx[row];
  int c = threadIdx.x;
  const float4* tp = (const float4*)(tok + (size_t)token * 1024);
  const float4* pp = (const float4*)(pos + (size_t)t * 1024);
  float4* xp = (float4*)(x + (size_t)row * 1024);
  float4 a = tp[c], b = pp[c];
  xp[c] = make_float4(a.x + b.x, a.y + b.y, a.z + b.z, a.w + b.w);
}

// ---------------- layernorm (f32 in) -> bf16 out ----------------
__global__ __launch_bounds__(256) void ln_kernel(
    const float* __restrict__ x, const float* __restrict__ g,
    const float* __restrict__ b, bf16* __restrict__ out) {
  int row = blockIdx.x, tid = threadIdx.x;
  const float4* xp = (const float4*)(x + (size_t)row * 1024);
  float4 v = xp[tid];
  float s = v.x + v.y + v.z + v.w;
  float q = v.x * v.x + v.y * v.y + v.z * v.z + v.w * v.w;
#pragma unroll
  for (int d = 1; d < 64; d <<= 1) {
    s += __shfl_xor(s, d);
    q += __shfl_xor(q, d);
  }
  __shared__ float red[8];
  int wid = tid >> 6, lane = tid & 63;
  if (lane == 0) { red[wid] = s; red[4 + wid] = q; }
  __syncthreads();
  s = red[0] + red[1] + red[2] + red[3];
  q = red[4] + red[5] + red[6] + red[7];
  float mean = s * (1.0f / 1024.0f);
  float var = q * (1.0f / 1024.0f) - mean * mean;
  float rs = rsqrtf(var + 1e-5f);
  float4 gv = ((const float4*)g)[tid];
  float4 bv = ((const float4*)b)[tid];
  bf16x4 o;
  o[0] = (bf16)((v.x - mean) * rs * gv.x + bv.x);
  o[1] = (bf16)((v.y - mean) * rs * gv.y + bv.y);
  o[2] = (bf16)((v.z - mean) * rs * gv.z + bv.z);
  o[3] = (bf16)((v.w - mean) * rs * gv.w + bv.w);
  *(bf16x4*)(out + (size_t)row * 1024 + tid * 4) = o;
}

// ---------------- transpose + f32->bf16: out[batch][C][R] = in[batch][R][C] ----------------
__global__ __launch_bounds__(256) void transpose_cvt(
    const float* __restrict__ in, bf16* __restrict__ outp, int R, int C) {
  __shared__ float tile[32][33];
  int bz = blockIdx.z;
  size_t base = (size_t)bz * R * C;
  int tx = threadIdx.x & 31, ty4 = (threadIdx.x >> 5) * 4;
  int ic = blockIdx.x * 32 + tx;
#pragma unroll
  for (int i = 0; i < 4; ++i) {
    int ir = blockIdx.y * 32 + ty4 + i;
    tile[ty4 + i][tx] = in[base + (size_t)ir * C + ic];
  }
  __syncthreads();
  int oc = blockIdx.y * 32 + tx;
#pragma unroll
  for (int i = 0; i < 4; ++i) {
    int orow = blockIdx.x * 32 + ty4 + i;
    outp[base + (size_t)orow * R + oc] = (bf16)tile[tx][ty4 + i];
  }
}

// ---------------- GEMM: C[M xN] = A[MxK] @ Bt[NxK]^T, bf16 in, f32 acc ----------------
// MODE 0: QKV scatter (out q[b,h,t,e], k[b,h,t,e], v^T[b,h,e,t], bf16)
// MODE 1: f32 out = res + acc + bias
// MODE 2: bf16 out = relu(acc + bias)
// MODE 3: f32 out = acc + bias
template <int MODE>
__global__ __launch_bounds__(256) void gemm_bt(
    const bf16* __restrict__ A, const bf16* __restrict__ Bt0,
    const bf16* __restrict__ Bt1, const bf16* __restrict__ Bt2,
    const float* __restrict__ bias, const float* __restrict__ res,
    void* __restrict__ out0, void* __restrict__ out1, void* __restrict__ out2,
    int N, int K) {
  __shared__ bf16 sA[128 * 64];  // linear [row][64] layout: global_load_lds dest
  __shared__ bf16 sB[128 * 64];
  const int tid = threadIdx.x;
  const int lane = tid & 63, wid = tid >> 6;
  const int quad = lane >> 4, l16 = lane & 15;
  const int wr = wid >> 1, wc = wid & 1;
  const int m0 = blockIdx.y * 128;
  const int n0g = blockIdx.x * 128;
  const bf16* Bt;
  int n0, proj = 0;
  if (MODE == 0) {
    proj = n0g >> 10;
    Bt = proj == 0 ? Bt0 : (proj == 1 ? Bt1 : Bt2);
    n0 = n0g & 1023;
  } else {
    Bt = Bt0;
    n0 = n0g;
  }

  f32x4 acc[4][4];
#pragma unroll
  for (int i = 0; i < 4; ++i)
#pragma unroll
    for (int j = 0; j < 4; ++j) acc[i][j] = f32x4{0.f, 0.f, 0.f, 0.f};

  for (int k0 = 0; k0 < K; k0 += 64) {
    __syncthreads();
#pragma unroll
    for (int it = 0; it < 4; ++it) {
      int o = (tid + it * 256) * 8;   // element offset into 128x64 tile
      int row = o >> 6, col = o & 63;
      GLOAD16(A + (size_t)(m0 + row) * K + k0 + col, sA + o);
      GLOAD16(Bt + (size_t)(n0 + row) * K + k0 + col, sB + o);
    }
    __syncthreads();  // drains vmcnt: LDS tiles complete
#pragma unroll
    for (int kc = 0; kc < 2; ++kc) {
      bf16x8 af[4], bfr[4];
#pragma unroll
      for (int i = 0; i < 4; ++i)
        af[i] = *(const bf16x8*)(sA + (wr * 64 + i * 16 + l16) * 64 + kc * 32 + quad * 8);
#pragma unroll
      for (int i = 0; i < 4; ++i)
        bfr[i] = *(const bf16x8*)(sB + (wc * 64 + i * 16 + l16) * 64 + kc * 32 + quad * 8);
#pragma unroll
      for (int mi = 0; mi < 4; ++mi)
#pragma unroll
        for (int ni = 0; ni < 4; ++ni)
          acc[mi][ni] = __builtin_amdgcn_mfma_f32_16x16x32_bf16(
              af[mi], bfr[ni], acc[mi][ni], 0, 0, 0);
    }
  }

#pragma unroll
  for (int mi = 0; mi < 4; ++mi)
#pragma unroll
    for (int ni = 0; ni < 4; ++ni)
#pragma unroll
      for (int r = 0; r < 4; ++r) {
        int m = m0 + wr * 64 + mi * 16 + quad * 4 + r;  // C row = quad*4+reg
        int nl = n0 + wc * 64 + ni * 16 + l16;          // C col = lane&15
        float v = acc[mi][ni][r];
        if (MODE == 0) {
          int b = m >> 10, t = m & 1023;
          int h = nl >> 6, e = nl & 63;
          bf16 val = (bf16)v;
          if (proj == 0)
            ((bf16*)out0)[(((size_t)b * 16 + h) * 1024 + t) * 64 + e] = val;
          else if (proj == 1)
            ((bf16*)out1)[(((size_t)b * 16 + h) * 1024 + t) * 64 + e] = val;
          else
            ((bf16*)out2)[(((size_t)b * 16 + h) * 64 + e) * 1024 + t] = val;
        } else if (MODE == 1) {
          ((float*)out0)[(size_t)m * N + nl] = res[(size_t)m * N + nl] + v + bias[nl];
        } else if (MODE == 2) {
          ((bf16*)out0)[(size_t)m * N + nl] = (bf16)fmaxf(v + bias[nl], 0.0f);
        } else {
          ((float*)out0)[(size_t)m * N + nl] = v + bias[nl];
        }
      }
}

// ---------------- flash attention: one block per (64-row Q tile, b*h) ----------------
__global__ __launch_bounds__(256) void attn_kernel(
    const bf16* __restrict__ q, const bf16* __restrict__ k,
    const bf16* __restrict__ vt, bf16* __restrict__ attn) {
  const int qt = blockIdx.x;   // 0..15
  const int bh = blockIdx.y;   // 0..31
  const int b = bh >> 4, h = bh & 15;
  const int tid = threadIdx.x;
  const int lane = tid & 63, wid = tid >> 6;
  const int quad = lane >> 4, l16 = lane & 15;
  __shared__ bf16 sK[64 * 72];
  __shared__ bf16 sV[64 * 72];      // V^T tile: [e][t]
  __shared__ bf16 sP[4][16 * 72];   // per-wave P strip
  const size_t qkbase = (size_t)bh * 1024 * 64;  // [bh][t][e]
  const size_t vbase = (size_t)bh * 64 * 1024;   // [bh][e][t]

  bf16x8 aq[2];  // Q strip A-frags: rows wid*16+l16, k=quad*8(+32)
  {
    const bf16* qp = q + qkbase + (size_t)(qt * 64 + wid * 16 + l16) * 64 + quad * 8;
    aq[0] = *(const bf16x8*)qp;
    aq[1] = *(const bf16x8*)(qp + 32);
  }
  f32x4 o[4];
#pragma unroll
  for (int i = 0; i < 4; ++i) o[i] = f32x4{0.f, 0.f, 0.f, 0.f};
  float m_run[4], l_run[4];
#pragma unroll
  for (int r = 0; r < 4; ++r) { m_run[r] = -1e30f; l_run[r] = 0.f; }

  for (int j = 0; j <= qt; ++j) {
    __syncthreads();
    {
      const bf16* kp = k + qkbase + (size_t)j * 64 * 64;
#pragma unroll
      for (int it = 0; it < 2; ++it) {
        int o8 = (tid + it * 256) * 8;
        int row = o8 >> 6, col = o8 & 63;
        *(bf16x8*)(sK + row * 72 + col) = *(const bf16x8*)(kp + o8);
        *(bf16x8*)(sV + row * 72 + col) =
            *(const bf16x8*)(vt + vbase + (size_t)row * 1024 + j * 64 + col);
      }
    }
    __syncthreads();

    f32x4 s[4];
#pragma unroll
    for (int nc = 0; nc < 4; ++nc) {
      f32x4 z = f32x4{0.f, 0.f, 0.f, 0.f};
      bf16x8 bk0 = *(const bf16x8*)(sK + (nc * 16 + l16) * 72 + quad * 8);
      z = __builtin_amdgcn_mfma_f32_16x16x32_bf16(aq[0], bk0, z, 0, 0, 0);
      bf16x8 bk1 = *(const bf16x8*)(sK + (nc * 16 + l16) * 72 + 32 + quad * 8);
      s[nc] = __builtin_amdgcn_mfma_f32_16x16x32_bf16(aq[1], bk1, z, 0, 0, 0);
    }
#pragma unroll
    for (int nc = 0; nc < 4; ++nc)
#pragma unroll
      for (int r = 0; r < 4; ++r) {
        float sv = s[nc][r] * 0.125f;  // HD^-0.5
        if (j == qt && (nc * 16 + l16) > (wid * 16 + quad * 4 + r)) sv = -1e30f;
        s[nc][r] = sv;
      }
    float mx[4];
#pragma unroll
    for (int r = 0; r < 4; ++r)
      mx[r] = fmaxf(fmaxf(s[0][r], s[1][r]), fmaxf(s[2][r], s[3][r]));
#pragma unroll
    for (int d = 1; d < 16; d <<= 1)
#pragma unroll
      for (int r = 0; r < 4; ++r) mx[r] = fmaxf(mx[r], __shfl_xor(mx[r], d));
    float al[4], rsum[4];
#pragma unroll
    for (int r = 0; r < 4; ++r) {
      float mn = fmaxf(m_run[r], mx[r]);
      al[r] = __expf(m_run[r] - mn);
      m_run[r] = mn;
    }
#pragma unroll
    for (int nc = 0; nc < 4; ++nc)
#pragma unroll
      for (int r = 0; r < 4; ++r) s[nc][r] = __expf(s[nc][r] - m_run[r]);
#pragma unroll
    for (int r = 0; r < 4; ++r) rsum[r] = s[0][r] + s[1][r] + s[2][r] + s[3][r];
#pragma unroll
    for (int d = 1; d < 16; d <<= 1)
#pragma unroll
      for (int r = 0; r < 4; ++r) rsum[r] += __shfl_xor(rsum[r], d);
#pragma unroll
    for (int r = 0; r < 4; ++r) l_run[r] = al[r] * l_run[r] + rsum[r];
    // rescale O, write P (C-layout -> LDS -> A-layout; same-wave DS in-order)
#pragma unroll
    for (int nc = 0; nc < 4; ++nc)
#pragma unroll
      for (int r = 0; r < 4; ++r) {
        o[nc][r] *= al[r];
        sP[wid][(quad * 4 + r) * 72 + nc * 16 + l16] = (bf16)s[nc][r];
      }
#pragma unroll
    for (int kc = 0; kc < 2; ++kc) {
      bf16x8 ap = *(const bf16x8*)(&sP[wid][l16 * 72 + kc * 32 + quad * 8]);
#pragma unroll
      for (int nc = 0; nc < 4; ++nc) {
        bf16x8 bv = *(const bf16x8*)(sV + (nc * 16 + l16) * 72 + kc * 32 + quad * 8);
        o[nc] = __builtin_amdgcn_mfma_f32_16x16x32_bf16(ap, bv, o[nc], 0, 0, 0);
      }
    }
  }
#pragma unroll
  for (int nc = 0; nc < 4; ++nc)
#pragma unroll
    for (int r = 0; r < 4; ++r) {
      int t = qt * 64 + wid * 16 + quad * 4 + r;
      int dcol = h * 64 + nc * 16 + l16;
      float val = o[nc][r] / l_run[r];
      attn[((size_t)b * 1024 + t) * 1024 + dcol] = (bf16)val;
    }
}

// ---------------- host ----------------
extern "C" void kernel_launch(void* const* d_in, const int* in_sizes, int n_in,
                              void* d_out, int out_size, void* d_ws, size_t ws_size,
                              hipStream_t stream) {
  const int* idx = (const int*)d_in[0];
  const float* tok_emb = (const float*)d_in[1];
  const float* pos_emb = (const float*)d_in[2];
  const float* Wq = (const float*)d_in[3];
  const float* Wk = (const float*)d_in[4];
  const float* Wv = (const float*)d_in[5];
  const float* Wo = (const float*)d_in[6];
  const float* bo = (const float*)d_in[7];
  const float* ln1_g = (const float*)d_in[8];
  const float* ln1_b = (const float*)d_in[9];
  const float* ln2_g = (const float*)d_in[10];
  const float* ln2_b = (const float*)d_in[11];
  const float* W1 = (const float*)d_in[12];
  const float* b1 = (const float*)d_in[13];
  const float* W2 = (const float*)d_in[14];
  const float* b2 = (const float*)d_in[15];
  const float* lnf_g = (const float*)d_in[16];
  const float* lnf_b = (const float*)d_in[17];
  const float* Wh = (const float*)d_in[18];
  const float* bh = (const float*)d_in[19];
  float* out = (float*)d_out;
  char* ws = (char*)d_ws;

  size_t off = 0;
  auto take = [&](size_t bytes) -> void* {
    void* p = ws + off;
    off += (bytes + 255) & ~(size_t)255;
    return p;
  };
  bf16* wqt = (bf16*)take(6ull * 16 * 64 * 1024 * 2);   // [l][h][e][d]
  bf16* wkt = (bf16*)take(6ull * 16 * 64 * 1024 * 2);
  bf16* wvt = (bf16*)take(6ull * 16 * 64 * 1024 * 2);
  bf16* wot = (bf16*)take(6ull * 1024 * 1024 * 2);      // [l][dout][din]
  bf16* w1t = (bf16*)take(6ull * 4096 * 1024 * 2);      // [l][f][d]
  bf16* w2t = (bf16*)take(6ull * 1024 * 4096 * 2);      // [l][d][f]
  bf16* wht = (bf16*)take(32000ull * 1024 * 2);         // [v][d]
  float* x = (float*)take(2048ull * 1024 * 4);
  bf16* hbuf = (bf16*)take(2048ull * 1024 * 2);
  bf16* qbuf = (bf16*)take(2ull * 16 * 1024 * 64 * 2);
  bf16* kbuf = (bf16*)take(2ull * 16 * 1024 * 64 * 2);
  bf16* vtbuf = (bf16*)take(2ull * 16 * 64 * 1024 * 2);
  bf16* abuf = (bf16*)take(2048ull * 1024 * 2);
  bf16* ffbuf = (bf16*)take(2048ull * 4096 * 2);
  (void)ws_size; (void)in_sizes; (void)n_in; (void)out_size;

  dim3 blk(256);
  transpose_cvt<<<dim3(2, 32, 96), blk, 0, stream>>>(Wq, wqt, 1024, 64);
  transpose_cvt<<<dim3(2, 32, 96), blk, 0, stream>>>(Wk, wkt, 1024, 64);
  transpose_cvt<<<dim3(2, 32, 96), blk, 0, stream>>>(Wv, wvt, 1024, 64);
  transpose_cvt<<<dim3(32, 32, 6), blk, 0, stream>>>(Wo, wot, 1024, 1024);
  transpose_cvt<<<dim3(128, 32, 6), blk, 0, stream>>>(W1, w1t, 1024, 4096);
  transpose_cvt<<<dim3(32, 128, 6), blk, 0, stream>>>(W2, w2t, 4096, 1024);
  transpose_cvt<<<dim3(1000, 32, 1), blk, 0, stream>>>(Wh, wht, 1024, 32000);

  embed_kernel<<<dim3(2048), blk, 0, stream>>>(idx, tok_emb, pos_emb, x);

  for (int l = 0; l < 6; ++l) {
    ln_kernel<<<dim3(2048), blk, 0, stream>>>(x, ln1_g + l * 1024, ln1_b + l * 1024, hbuf);
    gemm_bt<0><<<dim3(24, 16), blk, 0, stream>>>(
        hbuf, wqt + (size_t)l * 1048576, wkt + (size_t)l * 1048576,
        wvt + (size_t)l * 1048576, nullptr, nullptr, qbuf, kbuf, vtbuf, 3072, 1024);
    attn_kernel<<<dim3(16, 32), blk, 0, stream>>>(qbuf, kbuf, vtbuf, abuf);
    gemm_bt<1><<<dim3(8, 16), blk, 0, stream>>>(
        abuf, wot + (size_t)l * 1048576, nullptr, nullptr, bo + l * 1024, x,
        x, nullptr, nullptr, 1024, 1024);
    ln_kernel<<<dim3(2048), blk, 0, stream>>>(x, ln2_g + l * 1024, ln2_b + l * 1024, hbuf);
    gemm_bt<2><<<dim3(32, 16), blk, 0, stream>>>(
        hbuf, w1t + (size_t)l * 4194304, nullptr, nullptr, b1 + l * 4096, nullptr,
        ffbuf, nullptr, nullptr, 4096, 1024);
    gemm_bt<1><<<dim3(8, 16), blk, 0, stream>>>(
        ffbuf, w2t + (size_t)l * 4194304, nullptr, nullptr, b2 + l * 1024, x,
        x, nullptr, nullptr, 1024, 4096);
  }
  ln_kernel<<<dim3(2048), blk, 0, stream>>>(x, lnf_g, lnf_b, hbuf);
  gemm_bt<3><<<dim3(250, 16), blk, 0, stream>>>(
      hbuf, wht, nullptr, nullptr, bh, nullptr, out, nullptr, nullptr, 32000, 1024);
}

// Round 2
// 2199.725 us; speedup vs baseline: 1.0626x; 1.0626x over previous
//
#include <hip/hip_runtime.h>

typedef __bf16 bf16;
typedef __bf16 bf16x8 __attribute__((ext_vector_type(8)));
typedef __bf16 bf16x4 __attribute__((ext_vector_type(4)));
typedef float f32x4 __attribute__((ext_vector_type(4)));

// direct global->LDS DMA, 16B per lane (dest must be linear: uniform base + lane*16)
#define GLOAD16(gptr, lptr)                                        \
  __builtin_amdgcn_global_load_lds(                                \
      (const __attribute__((address_space(1))) void*)(gptr),       \
      (__attribute__((address_space(3))) void*)(lptr), 16, 0, 0)

// ---------------- embedding: x = tok_emb[idx] + pos_emb ----------------
__global__ __launch_bounds__(256) void embed_kernel(
    const int* __restrict__ idx, const float* __restrict__ tok,
    const float* __restrict__ pos, float* __restrict__ x) {
  int row = blockIdx.x;           // b*1024 + t
  int t = row & 1023;
  int token = idx[row];
  int c = threadIdx.x;
  const float4* tp = (const float4*)(tok + (size_t)token * 1024);
  const float4* pp = (const float4*)(pos + (size_t)t * 1024);
  float4* xp = (float4*)(x + (size_t)row * 1024);
  float4 a = tp[c], b = pp[c];
  xp[c] = make_float4(a.x + b.x, a.y + b.y, a.z + b.z, a.w + b.w);
}

// ---------------- layernorm (f32 in) -> bf16 out ----------------
__global__ __launch_bounds__(256) void ln_kernel(
    const float* __restrict__ x, const float* __restrict__ g,
    const float* __restrict__ b, bf16* __restrict__ out) {
  int row = blockIdx.x, tid = threadIdx.x;
  const float4* xp = (const float4*)(x + (size_t)row * 1024);
  float4 v = xp[tid];
  float s = v.x + v.y + v.z + v.w;
  float q = v.x * v.x + v.y * v.y + v.z * v.z + v.w * v.w;
#pragma unroll
  for (int d = 1; d < 64; d <<= 1) {
    s += __shfl_xor(s, d);
    q += __shfl_xor(q, d);
  }
  __shared__ float red[8];
  int wid = tid >> 6, lane = tid & 63;
  if (lane == 0) { red[wid] = s; red[4 + wid] = q; }
  __syncthreads();
  s = red[0] + red[1] + red[2] + red[3];
  q = red[4] + red[5] + red[6] + red[7];
  float mean = s * (1.0f / 1024.0f);
  float var = q * (1.0f / 1024.0f) - mean * mean;
  float rs = rsqrtf(var + 1e-5f);
  float4 gv = ((const float4*)g)[tid];
  float4 bv = ((const float4*)b)[tid];
  bf16x4 o;
  o[0] = (bf16)((v.x - mean) * rs * gv.x + bv.x);
  o[1] = (bf16)((v.y - mean) * rs * gv.y + bv.y);
  o[2] = (bf16)((v.z - mean) * rs * gv.z + bv.z);
  o[3] = (bf16)((v.w - mean) * rs * gv.w + bv.w);
  *(bf16x4*)(out + (size_t)row * 1024 + tid * 4) = o;
}

// ---------------- transpose + f32->bf16: out[batch][C][R] = in[batch][R][C] ----------------
__global__ __launch_bounds__(256) void transpose_cvt(
    const float* __restrict__ in, bf16* __restrict__ outp, int R, int C) {
  __shared__ float tile[32][33];
  int bz = blockIdx.z;
  size_t base = (size_t)bz * R * C;
  int tx = threadIdx.x & 31, ty4 = (threadIdx.x >> 5) * 4;
  int ic = blockIdx.x * 32 + tx;
#pragma unroll
  for (int i = 0; i < 4; ++i) {
    int ir = blockIdx.y * 32 + ty4 + i;
    tile[ty4 + i][tx] = in[base + (size_t)ir * C + ic];
  }
  __syncthreads();
  int oc = blockIdx.y * 32 + tx;
#pragma unroll
  for (int i = 0; i < 4; ++i) {
    int orow = blockIdx.x * 32 + ty4 + i;
    outp[base + (size_t)orow * R + oc] = (bf16)tile[tx][ty4 + i];
  }
}

// ---------------- GEMM: C[MxN] = A[MxK] @ Bt[NxK]^T, bf16 in, f32 acc ----------------
// Grid: blockIdx.x = M tile (fast axis -> consecutive blocks share B-panel),
//       blockIdx.y = N tile.
// LDS: linear [128][64] dest for global_load_lds; 16B-slot XOR swizzle
//      (slot ^= row&7) applied on BOTH global source and LDS read (rule 21).
// MODE 0: QKV scatter (out q[b,h,t,e], k[b,h,t,e], v^T[b,h,e,t], bf16)
// MODE 1: f32 out = res + acc + bias
// MODE 2: bf16 out = relu(acc + bias)
// MODE 3: f32 out = acc + bias
template <int MODE>
__global__ __launch_bounds__(256) void gemm_bt(
    const bf16* __restrict__ A, const bf16* __restrict__ Bt0,
    const bf16* __restrict__ Bt1, const bf16* __restrict__ Bt2,
    const float* __restrict__ bias, const float* __restrict__ res,
    void* __restrict__ out0, void* __restrict__ out1, void* __restrict__ out2,
    int N, int K) {
  __shared__ bf16 sA[128 * 64];
  __shared__ bf16 sB[128 * 64];
  const int tid = threadIdx.x;
  const int lane = tid & 63, wid = tid >> 6;
  const int quad = lane >> 4, l16 = lane & 15;
  const int wr = wid >> 1, wc = wid & 1;
  const int m0 = blockIdx.x * 128;
  const int n0g = blockIdx.y * 128;
  const bf16* Bt;
  int n0, proj = 0;
  if (MODE == 0) {
    proj = n0g >> 10;
    Bt = proj == 0 ? Bt0 : (proj == 1 ? Bt1 : Bt2);
    n0 = n0g & 1023;
  } else {
    Bt = Bt0;
    n0 = n0g;
  }

  f32x4 acc[4][4];
#pragma unroll
  for (int i = 0; i < 4; ++i)
#pragma unroll
    for (int j = 0; j < 4; ++j) acc[i][j] = f32x4{0.f, 0.f, 0.f, 0.f};

  for (int k0 = 0; k0 < K; k0 += 64) {
    __syncthreads();
#pragma unroll
    for (int it = 0; it < 4; ++it) {
      int e = (tid + it * 256) * 8;     // element offset into 128x64 tile
      int row = e >> 6;
      int slot = (e >> 3) & 7;          // 16B slot within row
      int src = slot ^ (row & 7);       // inverse swizzle on global source
      GLOAD16(A + (size_t)(m0 + row) * K + k0 + src * 8, sA + e);
      GLOAD16(Bt + (size_t)(n0 + row) * K + k0 + src * 8, sB + e);
    }
    __syncthreads();  // drains vmcnt: LDS tiles complete
#pragma unroll
    for (int kc = 0; kc < 2; ++kc) {
      bf16x8 af[4], bfr[4];
#pragma unroll
      for (int i = 0; i < 4; ++i) {
        int row = wr * 64 + i * 16 + l16;
        int boff = (kc * 32 + quad * 8) ^ ((row & 7) << 3);  // swizzled read
        af[i] = *(const bf16x8*)(sA + row * 64 + boff);
      }
#pragma unroll
      for (int i = 0; i < 4; ++i) {
        int row = wc * 64 + i * 16 + l16;
        int boff = (kc * 32 + quad * 8) ^ ((row & 7) << 3);
        bfr[i] = *(const bf16x8*)(sB + row * 64 + boff);
      }
#pragma unroll
      for (int mi = 0; mi < 4; ++mi)
#pragma unroll
        for (int ni = 0; ni < 4; ++ni)
          acc[mi][ni] = __builtin_amdgcn_mfma_f32_16x16x32_bf16(
              af[mi], bfr[ni], acc[mi][ni], 0, 0, 0);
    }
  }

#pragma unroll
  for (int mi = 0; mi < 4; ++mi)
#pragma unroll
    for (int ni = 0; ni < 4; ++ni)
#pragma unroll
      for (int r = 0; r < 4; ++r) {
        int m = m0 + wr * 64 + mi * 16 + quad * 4 + r;  // C row = quad*4+reg
        int nl = n0 + wc * 64 + ni * 16 + l16;          // C col = lane&15
        float v = acc[mi][ni][r];
        if (MODE == 0) {
          int b = m >> 10, t = m & 1023;
          int h = nl >> 6, e = nl & 63;
          bf16 val = (bf16)v;
          if (proj == 0)
            ((bf16*)out0)[(((size_t)b * 16 + h) * 1024 + t) * 64 + e] = val;
          else if (proj == 1)
            ((bf16*)out1)[(((size_t)b * 16 + h) * 1024 + t) * 64 + e] = val;
          else
            ((bf16*)out2)[(((size_t)b * 16 + h) * 64 + e) * 1024 + t] = val;
        } else if (MODE == 1) {
          ((float*)out0)[(size_t)m * N + nl] = res[(size_t)m * N + nl] + v + bias[nl];
        } else if (MODE == 2) {
          ((bf16*)out0)[(size_t)m * N + nl] = (bf16)fmaxf(v + bias[nl], 0.0f);
        } else {
          ((float*)out0)[(size_t)m * N + nl] = v + bias[nl];
        }
      }
}

// ---------------- flash attention: one block per (64-row Q tile, b*h) ----------------
__global__ __launch_bounds__(256) void attn_kernel(
    const bf16* __restrict__ q, const bf16* __restrict__ k,
    const bf16* __restrict__ vt, bf16* __restrict__ attn) {
  const int qt = blockIdx.x;   // 0..15
  const int bh = blockIdx.y;   // 0..31
  const int b = bh >> 4, h = bh & 15;
  const int tid = threadIdx.x;
  const int lane = tid & 63, wid = tid >> 6;
  const int quad = lane >> 4, l16 = lane & 15;
  __shared__ bf16 sK[64 * 72];
  __shared__ bf16 sV[64 * 72];      // V^T tile: [e][t]
  __shared__ bf16 sP[4][16 * 72];   // per-wave P strip
  const size_t qkbase = (size_t)bh * 1024 * 64;  // [bh][t][e]
  const size_t vbase = (size_t)bh * 64 * 1024;   // [bh][e][t]

  bf16x8 aq[2];  // Q strip A-frags: rows wid*16+l16, k=quad*8(+32)
  {
    const bf16* qp = q + qkbase + (size_t)(qt * 64 + wid * 16 + l16) * 64 + quad * 8;
    aq[0] = *(const bf16x8*)qp;
    aq[1] = *(const bf16x8*)(qp + 32);
  }
  f32x4 o[4];
#pragma unroll
  for (int i = 0; i < 4; ++i) o[i] = f32x4{0.f, 0.f, 0.f, 0.f};
  float m_run[4], l_run[4];
#pragma unroll
  for (int r = 0; r < 4; ++r) { m_run[r] = -1e30f; l_run[r] = 0.f; }

  for (int j = 0; j <= qt; ++j) {
    __syncthreads();
    {
      const bf16* kp = k + qkbase + (size_t)j * 64 * 64;
#pragma unroll
      for (int it = 0; it < 2; ++it) {
        int o8 = (tid + it * 256) * 8;
        int row = o8 >> 6, col = o8 & 63;
        *(bf16x8*)(sK + row * 72 + col) = *(const bf16x8*)(kp + o8);
        *(bf16x8*)(sV + row * 72 + col) =
            *(const bf16x8*)(vt + vbase + (size_t)row * 1024 + j * 64 + col);
      }
    }
    __syncthreads();

    f32x4 s[4];
#pragma unroll
    for (int nc = 0; nc < 4; ++nc) {
      f32x4 z = f32x4{0.f, 0.f, 0.f, 0.f};
      bf16x8 bk0 = *(const bf16x8*)(sK + (nc * 16 + l16) * 72 + quad * 8);
      z = __builtin_amdgcn_mfma_f32_16x16x32_bf16(aq[0], bk0, z, 0, 0, 0);
      bf16x8 bk1 = *(const bf16x8*)(sK + (nc * 16 + l16) * 72 + 32 + quad * 8);
      s[nc] = __builtin_amdgcn_mfma_f32_16x16x32_bf16(aq[1], bk1, z, 0, 0, 0);
    }
#pragma unroll
    for (int nc = 0; nc < 4; ++nc)
#pragma unroll
      for (int r = 0; r < 4; ++r) {
        float sv = s[nc][r] * 0.125f;  // HD^-0.5
        if (j == qt && (nc * 16 + l16) > (wid * 16 + quad * 4 + r)) sv = -1e30f;
        s[nc][r] = sv;
      }
    float mx[4];
#pragma unroll
    for (int r = 0; r < 4; ++r)
      mx[r] = fmaxf(fmaxf(s[0][r], s[1][r]), fmaxf(s[2][r], s[3][r]));
#pragma unroll
    for (int d = 1; d < 16; d <<= 1)
#pragma unroll
      for (int r = 0; r < 4; ++r) mx[r] = fmaxf(mx[r], __shfl_xor(mx[r], d));
    float al[4], rsum[4];
#pragma unroll
    for (int r = 0; r < 4; ++r) {
      float mn = fmaxf(m_run[r], mx[r]);
      al[r] = __expf(m_run[r] - mn);
      m_run[r] = mn;
    }
#pragma unroll
    for (int nc = 0; nc < 4; ++nc)
#pragma unroll
      for (int r = 0; r < 4; ++r) s[nc][r] = __expf(s[nc][r] - m_run[r]);
#pragma unroll
    for (int r = 0; r < 4; ++r) rsum[r] = s[0][r] + s[1][r] + s[2][r] + s[3][r];
#pragma unroll
    for (int d = 1; d < 16; d <<= 1)
#pragma unroll
      for (int r = 0; r < 4; ++r) rsum[r] += __shfl_xor(rsum[r], d);
#pragma unroll
    for (int r = 0; r < 4; ++r) l_run[r] = al[r] * l_run[r] + rsum[r];
    // rescale O, write P (C-layout -> LDS -> A-layout; same-wave DS in-order)
#pragma unroll
    for (int nc = 0; nc < 4; ++nc)
#pragma unroll
      for (int r = 0; r < 4; ++r) {
        o[nc][r] *= al[r];
        sP[wid][(quad * 4 + r) * 72 + nc * 16 + l16] = (bf16)s[nc][r];
      }
#pragma unroll
    for (int kc = 0; kc < 2; ++kc) {
      bf16x8 ap = *(const bf16x8*)(&sP[wid][l16 * 72 + kc * 32 + quad * 8]);
#pragma unroll
      for (int nc = 0; nc < 4; ++nc) {
        bf16x8 bv = *(const bf16x8*)(sV + (nc * 16 + l16) * 72 + kc * 32 + quad * 8);
        o[nc] = __builtin_amdgcn_mfma_f32_16x16x32_bf16(ap, bv, o[nc], 0, 0, 0);
      }
    }
  }
#pragma unroll
  for (int nc = 0; nc < 4; ++nc)
#pragma unroll
    for (int r = 0; r < 4; ++r) {
      int t = qt * 64 + wid * 16 + quad * 4 + r;
      int dcol = h * 64 + nc * 16 + l16;
      float val = o[nc][r] / l_run[r];
      attn[((size_t)b * 1024 + t) * 1024 + dcol] = (bf16)val;
    }
}

// ---------------- host ----------------
extern "C" void kernel_launch(void* const* d_in, const int* in_sizes, int n_in,
                              void* d_out, int out_size, void* d_ws, size_t ws_size,
                              hipStream_t stream) {
  const int* idx = (const int*)d_in[0];
  const float* tok_emb = (const float*)d_in[1];
  const float* pos_emb = (const float*)d_in[2];
  const float* Wq = (const float*)d_in[3];
  const float* Wk = (const float*)d_in[4];
  const float* Wv = (const float*)d_in[5];
  const float* Wo = (const float*)d_in[6];
  const float* bo = (const float*)d_in[7];
  const float* ln1_g = (const float*)d_in[8];
  const float* ln1_b = (const float*)d_in[9];
  const float* ln2_g = (const float*)d_in[10];
  const float* ln2_b = (const float*)d_in[11];
  const float* W1 = (const float*)d_in[12];
  const float* b1 = (const float*)d_in[13];
  const float* W2 = (const float*)d_in[14];
  const float* b2 = (const float*)d_in[15];
  const float* lnf_g = (const float*)d_in[16];
  const float* lnf_b = (const float*)d_in[17];
  const float* Wh = (const float*)d_in[18];
  const float* bh = (const float*)d_in[19];
  float* out = (float*)d_out;
  char* ws = (char*)d_ws;

  size_t off = 0;
  auto take = [&](size_t bytes) -> void* {
    void* p = ws + off;
    off += (bytes + 255) & ~(size_t)255;
    return p;
  };
  bf16* wqt = (bf16*)take(6ull * 16 * 64 * 1024 * 2);   // [l][h][e][d]
  bf16* wkt = (bf16*)take(6ull * 16 * 64 * 1024 * 2);
  bf16* wvt = (bf16*)take(6ull * 16 * 64 * 1024 * 2);
  bf16* wot = (bf16*)take(6ull * 1024 * 1024 * 2);      // [l][dout][din]
  bf16* w1t = (bf16*)take(6ull * 4096 * 1024 * 2);      // [l][f][d]
  bf16* w2t = (bf16*)take(6ull * 1024 * 4096 * 2);      // [l][d][f]
  bf16* wht = (bf16*)take(32000ull * 1024 * 2);         // [v][d]
  float* x = (float*)take(2048ull * 1024 * 4);
  bf16* hbuf = (bf16*)take(2048ull * 1024 * 2);
  bf16* qbuf = (bf16*)take(2ull * 16 * 1024 * 64 * 2);
  bf16* kbuf = (bf16*)take(2ull * 16 * 1024 * 64 * 2);
  bf16* vtbuf = (bf16*)take(2ull * 16 * 64 * 1024 * 2);
  bf16* abuf = (bf16*)take(2048ull * 1024 * 2);
  bf16* ffbuf = (bf16*)take(2048ull * 4096 * 2);
  (void)ws_size; (void)in_sizes; (void)n_in; (void)out_size;

  dim3 blk(256);
  transpose_cvt<<<dim3(2, 32, 96), blk, 0, stream>>>(Wq, wqt, 1024, 64);
  transpose_cvt<<<dim3(2, 32, 96), blk, 0, stream>>>(Wk, wkt, 1024, 64);
  transpose_cvt<<<dim3(2, 32, 96), blk, 0, stream>>>(Wv, wvt, 1024, 64);
  transpose_cvt<<<dim3(32, 32, 6), blk, 0, stream>>>(Wo, wot, 1024, 1024);
  transpose_cvt<<<dim3(128, 32, 6), blk, 0, stream>>>(W1, w1t, 1024, 4096);
  transpose_cvt<<<dim3(32, 128, 6), blk, 0, stream>>>(W2, w2t, 4096, 1024);
  transpose_cvt<<<dim3(1000, 32, 1), blk, 0, stream>>>(Wh, wht, 1024, 32000);

  embed_kernel<<<dim3(2048), blk, 0, stream>>>(idx, tok_emb, pos_emb, x);

  for (int l = 0; l < 6; ++l) {
    ln_kernel<<<dim3(2048), blk, 0, stream>>>(x, ln1_g + l * 1024, ln1_b + l * 1024, hbuf);
    gemm_bt<0><<<dim3(16, 24), blk, 0, stream>>>(
        hbuf, wqt + (size_t)l * 1048576, wkt + (size_t)l * 1048576,
        wvt + (size_t)l * 1048576, nullptr, nullptr, qbuf, kbuf, vtbuf, 3072, 1024);
    attn_kernel<<<dim3(16, 32), blk, 0, stream>>>(qbuf, kbuf, vtbuf, abuf);
    gemm_bt<1><<<dim3(16, 8), blk, 0, stream>>>(
        abuf, wot + (size_t)l * 1048576, nullptr, nullptr, bo + l * 1024, x,
        x, nullptr, nullptr, 1024, 1024);
    ln_kernel<<<dim3(2048), blk, 0, stream>>>(x, ln2_g + l * 1024, ln2_b + l * 1024, hbuf);
    gemm_bt<2><<<dim3(16, 32), blk, 0, stream>>>(
        hbuf, w1t + (size_t)l * 4194304, nullptr, nullptr, b1 + l * 4096, nullptr,
        ffbuf, nullptr, nullptr, 4096, 1024);
    gemm_bt<1><<<dim3(16, 8), blk, 0, stream>>>(
        ffbuf, w2t + (size_t)l * 4194304, nullptr, nullptr, b2 + l * 1024, x,
        x, nullptr, nullptr, 1024, 4096);
  }
  ln_kernel<<<dim3(2048), blk, 0, stream>>>(x, lnf_g, lnf_b, hbuf);
  gemm_bt<3><<<dim3(16, 250), blk, 0, stream>>>(
      hbuf, wht, nullptr, nullptr, bh, nullptr, out, nullptr, nullptr, 32000, 1024);
}